// Round 1
// baseline (1037.451 us; speedup 1.0000x reference)
//
#include <hip/hip_runtime.h>
#include <math.h>

#define BN 8
#define AN 76725
#define CN 80
#define MAXDET 50
#define MCAND 5120
#define NBINS 1024
#define NEGINF (-__builtin_inff())

// -------- Phase A: per-anchor score = max over 80 classes, cls = argmax (first max),
//          plus per-batch histogram of score bit-distance-from-1.0 for adaptive top-K.
__global__ __launch_bounds__(256) void k_score(
    const float* __restrict__ clsh,
    float* __restrict__ scr, int* __restrict__ clsv,
    unsigned* __restrict__ hist)
{
    int t = blockIdx.x * 256 + threadIdx.x;
    if (t >= BN * AN) return;
    int b = t / AN;
    const float4* p = reinterpret_cast<const float4*>(clsh + (size_t)t * CN);
    float best = -1.0f; int bi = 0;
    #pragma unroll
    for (int i = 0; i < CN / 4; ++i) {
        float4 v = p[i];
        if (v.x > best) { best = v.x; bi = 4*i+0; }   // strict > keeps FIRST max (jnp.argmax)
        if (v.y > best) { best = v.y; bi = 4*i+1; }
        if (v.z > best) { best = v.z; bi = 4*i+2; }
        if (v.w > best) { best = v.w; bi = 4*i+3; }
    }
    float s = (best > 0.1f) ? best : NEGINF;          // SCORE_THR mask, strict > like ref
    scr[t] = s;
    clsv[t] = bi;
    if (s != NEGINF) {
        unsigned u = __float_as_uint(s);
        unsigned d = (u < 0x3F800000u) ? (0x3F800000u - u) : 0u;  // ulp distance below 1.0
        unsigned bin = d >> 13; if (bin > NBINS - 1) bin = NBINS - 1;
        atomicAdd(&hist[b * NBINS + bin], 1u);
    }
}

// -------- pick per-batch bin threshold: largest prefix (from highest scores) with count <= MCAND
__global__ __launch_bounds__(NBINS) void k_select(
    const unsigned* __restrict__ hist, unsigned* __restrict__ bsel)
{
    __shared__ unsigned cum[NBINS];
    __shared__ int sel;
    int b = blockIdx.x, t = threadIdx.x;
    cum[t] = hist[b * NBINS + t];
    if (t == 0) sel = 0;
    __syncthreads();
    for (int off = 1; off < NBINS; off <<= 1) {       // Hillis-Steele inclusive scan
        unsigned v = (t >= off) ? cum[t - off] : 0u;
        __syncthreads();
        cum[t] += v;
        __syncthreads();
    }
    if (cum[t] <= MCAND && (t == NBINS - 1 || cum[t + 1] > MCAND)) atomicMax(&sel, t);
    __syncthreads();
    if (t == 0) bsel[b] = (unsigned)sel;
}

// -------- compact candidates (score in top bins) + decode their boxes exactly like the ref:
//          separate f32 roundings (no FMA), exp via double = correctly-rounded f32 exp.
__global__ __launch_bounds__(256) void k_compact(
    const float* __restrict__ scr, const int* __restrict__ clsv,
    const unsigned* __restrict__ bsel,
    const float* __restrict__ regh, const float* __restrict__ anch,
    unsigned* __restrict__ ncand,
    float* __restrict__ cscore, int* __restrict__ cmeta, float* __restrict__ cbox)
{
    int t = blockIdx.x * 256 + threadIdx.x;
    if (t >= BN * AN) return;
    float s = scr[t];
    if (s == NEGINF) return;
    int b = t / AN, a = t - b * AN;
    unsigned u = __float_as_uint(s);
    unsigned d = (u < 0x3F800000u) ? (0x3F800000u - u) : 0u;
    unsigned bin = d >> 13; if (bin > NBINS - 1) bin = NBINS - 1;
    if (bin > bsel[b]) return;
    unsigned slot = atomicAdd(&ncand[b], 1u);
    if (slot >= MCAND) return;

    float4 rg = reinterpret_cast<const float4*>(regh)[t];
    float4 an = reinterpret_cast<const float4*>(anch)[t];
    float aw  = __fsub_rn(an.z, an.x);
    float ah  = __fsub_rn(an.w, an.y);
    float acx = __fadd_rn(an.x, 0.5f * aw);
    float acy = __fadd_rn(an.y, 0.5f * ah);
    float rx  = __fmul_rn(rg.x, 0.1f);
    float ry  = __fmul_rn(rg.y, 0.1f);
    float rw  = __fmul_rn(rg.z, 0.2f);
    float rh  = __fmul_rn(rg.w, 0.2f);
    float pw  = __fmul_rn((float)exp((double)rw), aw);   // correctly-rounded f32 exp
    float ph  = __fmul_rn((float)exp((double)rh), ah);
    float pcx = __fadd_rn(__fmul_rn(rx, aw), acx);
    float pcy = __fadd_rn(__fmul_rn(ry, ah), acy);
    float x1 = fmaxf(truncf(__fsub_rn(pcx, 0.5f * pw)), 0.f);
    float y1 = fmaxf(truncf(__fsub_rn(pcy, 0.5f * ph)), 0.f);
    float x2 = fminf(truncf(__fadd_rn(pcx, 0.5f * pw)), 639.f);
    float y2 = fminf(truncf(__fadd_rn(pcy, 0.5f * ph)), 639.f);

    size_t ci = (size_t)b * MCAND + slot;
    cscore[ci] = s;
    cmeta[ci]  = a | (clsv[t] << 17);                  // idx<2^17, cls in upper bits
    reinterpret_cast<float4*>(cbox)[ci] = make_float4(x1, y1, x2, y2);
}

// -------- 50-step greedy NMS over candidates; one block per batch.
//          Lazy suppression: each iteration applies the previous winner to all j,
//          fused with the argmax pass. Tie-break = lowest original anchor index.
__global__ __launch_bounds__(1024) void k_nms(
    const unsigned* __restrict__ ncand,
    const float* __restrict__ cscore,
    const int* __restrict__ cmeta,
    const float* __restrict__ cbox,
    float* __restrict__ out)
{
    __shared__ float ssc[MCAND];
    __shared__ int   smeta[MCAND];
    __shared__ float red_s[16];
    __shared__ int   red_i[16], red_j[16];
    __shared__ int   wsel_j_s;
    __shared__ float wsel_s_s;

    const int b = blockIdx.x;
    const int t = threadIdx.x;
    const int lane = t & 63, wid = t >> 6;
    const int n = min((int)ncand[b], MCAND);
    const float4* cb = reinterpret_cast<const float4*>(cbox) + (size_t)b * MCAND;

    for (int j = t; j < n; j += 1024) {
        ssc[j]   = cscore[(size_t)b * MCAND + j];
        smeta[j] = cmeta[(size_t)b * MCAND + j];
    }
    __syncthreads();

    int wj = -1, wcls = -1;
    float wx1 = 0, wy1 = 0, wx2 = 0, wy2 = 0, warea = 0;

    for (int k = 0; k < MAXDET; ++k) {
        float bs = NEGINF; int bidx = 0x7FFFFFFF; int bj = -1;
        for (int j = t; j < n; j += 1024) {
            float s = ssc[j];
            if (s == NEGINF) continue;
            if (wj >= 0) {
                if (j == wj) { ssc[j] = NEGINF; continue; }
                int m = smeta[j];
                if ((m >> 17) == wcls) {
                    float4 bx = cb[j];
                    float xx1 = fmaxf(bx.x, wx1);
                    float yy1 = fmaxf(bx.y, wy1);
                    float xx2 = fminf(bx.z, wx2);
                    float yy2 = fminf(bx.w, wy2);
                    float inter = fmaxf(xx2 - xx1, 0.f) * fmaxf(yy2 - yy1, 0.f);
                    float area = (bx.z - bx.x) * (bx.w - bx.y);   // exact int arithmetic in f32
                    float uni = area + warea - inter;
                    float iou = (uni > 0.f) ? (inter / uni) : 0.f;
                    if (iou > 0.5f) { ssc[j] = NEGINF; continue; }
                }
            }
            int idx = smeta[j] & 0x1FFFF;
            if (s > bs || (s == bs && idx < bidx)) { bs = s; bidx = idx; bj = j; }
        }
        #pragma unroll
        for (int m = 1; m < 64; m <<= 1) {
            float os = __shfl_xor(bs, m, 64);
            int oi = __shfl_xor(bidx, m, 64);
            int oj = __shfl_xor(bj, m, 64);
            if (os > bs || (os == bs && oi < bidx)) { bs = os; bidx = oi; bj = oj; }
        }
        if (lane == 0) { red_s[wid] = bs; red_i[wid] = bidx; red_j[wid] = bj; }
        __syncthreads();
        if (wid == 0) {
            bs   = (lane < 16) ? red_s[lane] : NEGINF;
            bidx = (lane < 16) ? red_i[lane] : 0x7FFFFFFF;
            bj   = (lane < 16) ? red_j[lane] : -1;
            #pragma unroll
            for (int m = 1; m < 16; m <<= 1) {
                float os = __shfl_xor(bs, m, 64);
                int oi = __shfl_xor(bidx, m, 64);
                int oj = __shfl_xor(bj, m, 64);
                if (os > bs || (os == bs && oi < bidx)) { bs = os; bidx = oi; bj = oj; }
            }
            if (lane == 0) { wsel_j_s = bj; wsel_s_s = bs; }
        }
        __syncthreads();
        int wjn = wsel_j_s;
        float wsc = wsel_s_s;
        bool ok = (wjn >= 0);
        float4 wb = make_float4(-1.f, -1.f, -1.f, -1.f);
        if (ok) {
            wb = cb[wjn];
            wcls = smeta[wjn] >> 17;
            wx1 = wb.x; wy1 = wb.y; wx2 = wb.z; wy2 = wb.w;
            warea = (wx2 - wx1) * (wy2 - wy1);
        }
        wj = ok ? wjn : -1;
        if (t == 0) {
            int o = b * MAXDET + k;
            out[o] = ok ? wsc : -1.f;
            out[BN * MAXDET + o] = ok ? (float)wcls : -1.f;
            float* ob = out + 2 * BN * MAXDET + 4 * o;
            ob[0] = wb.x; ob[1] = wb.y; ob[2] = wb.z; ob[3] = wb.w;
        }
    }
}

extern "C" void kernel_launch(void* const* d_in, const int* in_sizes, int n_in,
                              void* d_out, int out_size, void* d_ws, size_t ws_size,
                              hipStream_t stream)
{
    const float* clsh = (const float*)d_in[0];
    const float* regh = (const float*)d_in[1];
    const float* anch = (const float*)d_in[2];
    float* out = (float*)d_out;

    char* w = (char*)d_ws;
    float*    scr    = (float*)w;    w += (size_t)BN * AN * 4;
    int*      clsv   = (int*)w;      w += (size_t)BN * AN * 4;
    unsigned* hist   = (unsigned*)w; w += (size_t)BN * NBINS * 4;
    unsigned* ncand  = (unsigned*)w; w += BN * 4;
    unsigned* bsel   = (unsigned*)w; w += BN * 4;
    float*    cscore = (float*)w;    w += (size_t)BN * MCAND * 4;
    int*      cmeta  = (int*)w;      w += (size_t)BN * MCAND * 4;
    float*    cbox   = (float*)w;    /* BN*MCAND*16 bytes */

    // zero hist + ncand + bsel (contiguous region)
    hipMemsetAsync(hist, 0, (size_t)(BN * NBINS + BN + BN) * 4, stream);

    int total = BN * AN;
    int g1 = (total + 255) / 256;
    k_score<<<g1, 256, 0, stream>>>(clsh, scr, clsv, hist);
    k_select<<<BN, NBINS, 0, stream>>>(hist, bsel);
    k_compact<<<g1, 256, 0, stream>>>(scr, clsv, bsel, regh, anch, ncand, cscore, cmeta, cbox);
    k_nms<<<BN, 1024, 0, stream>>>(ncand, cscore, cmeta, cbox, out);
}

// Round 2
// 544.348 us; speedup vs baseline: 1.9059x; 1.9059x over previous
//
#include <hip/hip_runtime.h>
#include <math.h>

#define BN 8
#define AN 76725
#define CN 80
#define MAXDET 50
#define MCAND 5120
#define NBINS 1024
#define NEGINF (-__builtin_inff())
#define ABLK ((AN + 255) / 256)   // 300 blocks per batch

// -------- Phase A: per-anchor score = max over 80 classes, cls = argmax (first max).
// Per-block LDS histogram of ulp-distance-from-1.0 bins, flushed once per block.
// Grid: (ABLK, BN) so every block is batch-pure.
__global__ __launch_bounds__(256) void k_score(
    const float* __restrict__ clsh,
    float* __restrict__ scr, int* __restrict__ clsv,
    unsigned* __restrict__ hist)
{
    __shared__ unsigned lh[NBINS];
    const int b = blockIdx.y;
    const int a = blockIdx.x * 256 + threadIdx.x;
    #pragma unroll
    for (int i = threadIdx.x; i < NBINS; i += 256) lh[i] = 0u;
    __syncthreads();

    if (a < AN) {
        const size_t t = (size_t)b * AN + a;
        const float4* p = reinterpret_cast<const float4*>(clsh + t * CN);
        float best = -1.0f; int bi = 0;
        #pragma unroll
        for (int i = 0; i < CN / 4; ++i) {
            float4 v = p[i];
            if (v.x > best) { best = v.x; bi = 4*i+0; }   // strict > keeps FIRST max (jnp.argmax)
            if (v.y > best) { best = v.y; bi = 4*i+1; }
            if (v.z > best) { best = v.z; bi = 4*i+2; }
            if (v.w > best) { best = v.w; bi = 4*i+3; }
        }
        float s = (best > 0.1f) ? best : NEGINF;          // SCORE_THR, strict > like ref
        scr[t] = s;
        clsv[t] = bi;
        if (s != NEGINF) {
            unsigned u = __float_as_uint(s);
            unsigned d = (u < 0x3F800000u) ? (0x3F800000u - u) : 0u;
            unsigned bin = d >> 13; if (bin > NBINS - 1) bin = NBINS - 1;
            atomicAdd(&lh[bin], 1u);                      // LDS atomic — cheap
        }
    }
    __syncthreads();
    for (int i = threadIdx.x; i < NBINS; i += 256) {
        unsigned v = lh[i];
        if (v) atomicAdd(&hist[b * NBINS + i], v);        // ~#nonzero-bins global atomics/block
    }
}

// -------- pick per-batch bin threshold: largest prefix (from highest scores) with count <= MCAND
__global__ __launch_bounds__(NBINS) void k_select(
    const unsigned* __restrict__ hist, unsigned* __restrict__ bsel)
{
    __shared__ unsigned cum[NBINS];
    __shared__ int sel;
    int b = blockIdx.x, t = threadIdx.x;
    cum[t] = hist[b * NBINS + t];
    if (t == 0) sel = 0;
    __syncthreads();
    for (int off = 1; off < NBINS; off <<= 1) {
        unsigned v = (t >= off) ? cum[t - off] : 0u;
        __syncthreads();
        cum[t] += v;
        __syncthreads();
    }
    if (cum[t] <= MCAND && (t == NBINS - 1 || cum[t + 1] > MCAND)) atomicMax(&sel, t);
    __syncthreads();
    if (t == 0) bsel[b] = (unsigned)sel;
}

// -------- compact candidates + exact ref-style decode.
// Wave-aggregated slot allocation: one atomicAdd per wave (ballot+popc prefix).
// Grid: (ABLK, BN) batch-pure.
__global__ __launch_bounds__(256) void k_compact(
    const float* __restrict__ scr, const int* __restrict__ clsv,
    const unsigned* __restrict__ bsel,
    const float* __restrict__ regh, const float* __restrict__ anch,
    unsigned* __restrict__ ncand,
    float* __restrict__ cscore, int* __restrict__ cmeta, float* __restrict__ cbox)
{
    const int b = blockIdx.y;
    const int a = blockIdx.x * 256 + threadIdx.x;
    const size_t t = (size_t)b * AN + a;

    bool cand = false;
    float s = NEGINF;
    if (a < AN) {
        s = scr[t];
        if (s != NEGINF) {
            unsigned u = __float_as_uint(s);
            unsigned d = (u < 0x3F800000u) ? (0x3F800000u - u) : 0u;
            unsigned bin = d >> 13; if (bin > NBINS - 1) bin = NBINS - 1;
            cand = (bin <= bsel[b]);
        }
    }

    unsigned long long mask = __ballot(cand);
    if (!cand) return;
    const int lane = threadIdx.x & 63;
    const int leader = __ffsll((long long)mask) - 1;
    unsigned base = 0;
    if (lane == leader) base = atomicAdd(&ncand[b], (unsigned)__popcll(mask));
    base = (unsigned)__shfl((int)base, leader, 64);
    unsigned slot = base + (unsigned)__popcll(mask & ((1ull << lane) - 1ull));
    if (slot >= MCAND) return;

    float4 rg = reinterpret_cast<const float4*>(regh)[t];
    float4 an = reinterpret_cast<const float4*>(anch)[t];
    float aw  = __fsub_rn(an.z, an.x);
    float ah  = __fsub_rn(an.w, an.y);
    float acx = __fadd_rn(an.x, 0.5f * aw);
    float acy = __fadd_rn(an.y, 0.5f * ah);
    float rx  = __fmul_rn(rg.x, 0.1f);
    float ry  = __fmul_rn(rg.y, 0.1f);
    float rw  = __fmul_rn(rg.z, 0.2f);
    float rh  = __fmul_rn(rg.w, 0.2f);
    float pw  = __fmul_rn((float)exp((double)rw), aw);   // correctly-rounded f32 exp
    float ph  = __fmul_rn((float)exp((double)rh), ah);
    float pcx = __fadd_rn(__fmul_rn(rx, aw), acx);
    float pcy = __fadd_rn(__fmul_rn(ry, ah), acy);
    float x1 = fmaxf(truncf(__fsub_rn(pcx, 0.5f * pw)), 0.f);
    float y1 = fmaxf(truncf(__fsub_rn(pcy, 0.5f * ph)), 0.f);
    float x2 = fminf(truncf(__fadd_rn(pcx, 0.5f * pw)), 639.f);
    float y2 = fminf(truncf(__fadd_rn(pcy, 0.5f * ph)), 639.f);

    size_t ci = (size_t)b * MCAND + slot;
    cscore[ci] = s;
    cmeta[ci]  = a | (clsv[t] << 17);                    // idx<2^17, cls in upper bits
    reinterpret_cast<float4*>(cbox)[ci] = make_float4(x1, y1, x2, y2);
}

// -------- 50-step greedy NMS over candidates; one block per batch.
__global__ __launch_bounds__(1024) void k_nms(
    const unsigned* __restrict__ ncand,
    const float* __restrict__ cscore,
    const int* __restrict__ cmeta,
    const float* __restrict__ cbox,
    float* __restrict__ out)
{
    __shared__ float ssc[MCAND];
    __shared__ int   smeta[MCAND];
    __shared__ float red_s[16];
    __shared__ int   red_i[16], red_j[16];
    __shared__ int   wsel_j_s;
    __shared__ float wsel_s_s;

    const int b = blockIdx.x;
    const int t = threadIdx.x;
    const int lane = t & 63, wid = t >> 6;
    const int n = min((int)ncand[b], MCAND);
    const float4* cb = reinterpret_cast<const float4*>(cbox) + (size_t)b * MCAND;

    for (int j = t; j < n; j += 1024) {
        ssc[j]   = cscore[(size_t)b * MCAND + j];
        smeta[j] = cmeta[(size_t)b * MCAND + j];
    }
    __syncthreads();

    int wj = -1, wcls = -1;
    float wx1 = 0, wy1 = 0, wx2 = 0, wy2 = 0, warea = 0;

    for (int k = 0; k < MAXDET; ++k) {
        float bs = NEGINF; int bidx = 0x7FFFFFFF; int bj = -1;
        for (int j = t; j < n; j += 1024) {
            float s = ssc[j];
            if (s == NEGINF) continue;
            if (wj >= 0) {
                if (j == wj) { ssc[j] = NEGINF; continue; }
                int m = smeta[j];
                if ((m >> 17) == wcls) {
                    float4 bx = cb[j];
                    float xx1 = fmaxf(bx.x, wx1);
                    float yy1 = fmaxf(bx.y, wy1);
                    float xx2 = fminf(bx.z, wx2);
                    float yy2 = fminf(bx.w, wy2);
                    float inter = fmaxf(xx2 - xx1, 0.f) * fmaxf(yy2 - yy1, 0.f);
                    float area = (bx.z - bx.x) * (bx.w - bx.y);
                    float uni = area + warea - inter;
                    float iou = (uni > 0.f) ? (inter / uni) : 0.f;
                    if (iou > 0.5f) { ssc[j] = NEGINF; continue; }
                }
            }
            int idx = smeta[j] & 0x1FFFF;
            if (s > bs || (s == bs && idx < bidx)) { bs = s; bidx = idx; bj = j; }
        }
        #pragma unroll
        for (int m = 1; m < 64; m <<= 1) {
            float os = __shfl_xor(bs, m, 64);
            int oi = __shfl_xor(bidx, m, 64);
            int oj = __shfl_xor(bj, m, 64);
            if (os > bs || (os == bs && oi < bidx)) { bs = os; bidx = oi; bj = oj; }
        }
        if (lane == 0) { red_s[wid] = bs; red_i[wid] = bidx; red_j[wid] = bj; }
        __syncthreads();
        if (wid == 0) {
            bs   = (lane < 16) ? red_s[lane] : NEGINF;
            bidx = (lane < 16) ? red_i[lane] : 0x7FFFFFFF;
            bj   = (lane < 16) ? red_j[lane] : -1;
            #pragma unroll
            for (int m = 1; m < 16; m <<= 1) {
                float os = __shfl_xor(bs, m, 64);
                int oi = __shfl_xor(bidx, m, 64);
                int oj = __shfl_xor(bj, m, 64);
                if (os > bs || (os == bs && oi < bidx)) { bs = os; bidx = oi; bj = oj; }
            }
            if (lane == 0) { wsel_j_s = bj; wsel_s_s = bs; }
        }
        __syncthreads();
        int wjn = wsel_j_s;
        float wsc = wsel_s_s;
        bool ok = (wjn >= 0);
        float4 wb = make_float4(-1.f, -1.f, -1.f, -1.f);
        if (ok) {
            wb = cb[wjn];
            wcls = smeta[wjn] >> 17;
            wx1 = wb.x; wy1 = wb.y; wx2 = wb.z; wy2 = wb.w;
            warea = (wx2 - wx1) * (wy2 - wy1);
        }
        wj = ok ? wjn : -1;
        if (t == 0) {
            int o = b * MAXDET + k;
            out[o] = ok ? wsc : -1.f;
            out[BN * MAXDET + o] = ok ? (float)wcls : -1.f;
            float* ob = out + 2 * BN * MAXDET + 4 * o;
            ob[0] = wb.x; ob[1] = wb.y; ob[2] = wb.z; ob[3] = wb.w;
        }
    }
}

extern "C" void kernel_launch(void* const* d_in, const int* in_sizes, int n_in,
                              void* d_out, int out_size, void* d_ws, size_t ws_size,
                              hipStream_t stream)
{
    const float* clsh = (const float*)d_in[0];
    const float* regh = (const float*)d_in[1];
    const float* anch = (const float*)d_in[2];
    float* out = (float*)d_out;

    char* w = (char*)d_ws;
    float*    scr    = (float*)w;    w += (size_t)BN * AN * 4;
    int*      clsv   = (int*)w;      w += (size_t)BN * AN * 4;
    unsigned* hist   = (unsigned*)w; w += (size_t)BN * NBINS * 4;
    unsigned* ncand  = (unsigned*)w; w += BN * 4;
    unsigned* bsel   = (unsigned*)w; w += BN * 4;
    float*    cscore = (float*)w;    w += (size_t)BN * MCAND * 4;
    int*      cmeta  = (int*)w;      w += (size_t)BN * MCAND * 4;
    float*    cbox   = (float*)w;    /* BN*MCAND*16 bytes */

    hipMemsetAsync(hist, 0, (size_t)(BN * NBINS + BN + BN) * 4, stream);

    dim3 g2(ABLK, BN);
    k_score<<<g2, 256, 0, stream>>>(clsh, scr, clsv, hist);
    k_select<<<BN, NBINS, 0, stream>>>(hist, bsel);
    k_compact<<<g2, 256, 0, stream>>>(scr, clsv, bsel, regh, anch, ncand, cscore, cmeta, cbox);
    k_nms<<<BN, 1024, 0, stream>>>(ncand, cscore, cmeta, cbox, out);
}